// Round 6
// baseline (370.719 us; speedup 1.0000x reference)
//
#include <hip/hip_runtime.h>

typedef short  s16x4 __attribute__((ext_vector_type(4)));
typedef short  s16x8 __attribute__((ext_vector_type(8)));
typedef float  f32x4 __attribute__((ext_vector_type(4)));

__device__ __forceinline__ unsigned short f2b(float f) {
    unsigned u = __float_as_uint(f);
    u = u + 0x7FFFu + ((u >> 16) & 1u);   // RNE
    return (unsigned short)(u >> 16);
}

__device__ __forceinline__ void gload16(const void* g, void* l) {
    __builtin_amdgcn_global_load_lds((const __attribute__((address_space(1))) unsigned*)g,
                                     (__attribute__((address_space(3))) unsigned*)l,
                                     16, 0, 0);
}

// slot swizzle, period 16 in px: spreads per-pixel 16B channel-slots across banks
__device__ __forceinline__ int swz(int x) { return (x ^ (x >> 2)) & 3; }

// ---------- Bv2[(j*32+k)*256 + a*16+b] = sum_c Z2[b,j,c] * Z3[c,k,a]  (bf16) ----------
__global__ __launch_bounds__(256) void v_kernel(const float* __restrict__ Z2,
                                                const float* __restrict__ Z3,
                                                short* __restrict__ Bv2) {
    __shared__ float z3t[8192];   // [c][a][k]
    __shared__ float z2s[256];    // [b][c]
    const int tid = threadIdx.x, j = blockIdx.x;
    for (int t = tid; t < 8192; t += 256) {
        float v = Z3[t];                     // Z3[c,k,a] flat = c*512 + k*16 + a
        int c = t >> 9, k = (t >> 4) & 31, a = t & 15;
        z3t[c * 512 + a * 32 + k] = v;
    }
    z2s[tid] = Z2[(tid >> 4) * 16384 + j * 16 + (tid & 15)];
    __syncthreads();
    const int a = tid >> 4, b = tid & 15;
    float z2r[16];
    #pragma unroll
    for (int c = 0; c < 16; ++c) z2r[c] = z2s[b * 16 + c];
    float s[32];
    #pragma unroll
    for (int k = 0; k < 32; ++k) s[k] = 0.f;
    #pragma unroll
    for (int c = 0; c < 16; ++c) {
        #pragma unroll
        for (int k4 = 0; k4 < 8; ++k4) {
            f32x4 v = *(const f32x4*)&z3t[c * 512 + a * 32 + k4 * 4];
            #pragma unroll
            for (int r = 0; r < 4; ++r) s[k4 * 4 + r] += z2r[c] * v[r];
        }
    }
    #pragma unroll
    for (int k = 0; k < 32; ++k)
        Bv2[(size_t)(j * 32 + k) * 256 + tid] = (short)f2b(s[k]);
}

// ---------- Z1r[i*256 + a*16+b] = Z1[a,i,b]  (bf16) ----------
__global__ __launch_bounds__(256) void z1r_kernel(const float* __restrict__ Z1,
                                                  short* __restrict__ Z1r) {
    __shared__ float z1s[4096];
    const int tid = threadIdx.x, i0 = blockIdx.x * 16;
    #pragma unroll
    for (int a = 0; a < 16; ++a)
        z1s[a * 256 + tid] = Z1[a * 16384 + i0 * 16 + tid];
    __syncthreads();
    #pragma unroll
    for (int il = 0; il < 16; ++il)
        Z1r[(size_t)(i0 + il) * 256 + tid] =
            (short)f2b(z1s[(tid >> 4) * 256 + il * 16 + (tid & 15)]);
}

// ---------- X_nhwc[j][i][k] = sum_ab Bv2[(j*32+k)][ab] * Z1r[i][ab]  (bf16 MFMA) ----------
__global__ __launch_bounds__(256) void gemm_kernel(const short* __restrict__ Bv2,
                                                   const short* __restrict__ Z1r,
                                                   short* __restrict__ X) {
    __shared__ short sA[128 * 32];
    __shared__ short sB[128 * 32];
    const int tid = threadIdx.x;
    const int w = tid >> 6, lane = tid & 63, lane15 = lane & 15, q = lane >> 4;
    const int wm = w >> 1, wn = w & 1;
    const int bid = blockIdx.x;
    const int l = (bid & 7) * 256 + (bid >> 3);      // XCD-chunked swizzle
    const int n0 = (l >> 3) * 128, i0 = (l & 7) * 128;
    const int rs = lane >> 2, sp = lane & 3;
    const int scol = (sp ^ swz(rs)) << 3;
    const int fl = swz(lane15);

    f32x4 acc[4][4];
    #pragma unroll
    for (int a = 0; a < 4; ++a)
        #pragma unroll
        for (int b = 0; b < 4; ++b) acc[a][b] = (f32x4)0;

    for (int kk = 0; kk < 256; kk += 32) {
        gload16(&Bv2[(size_t)(n0 + w * 16 + rs) * 256 + kk + scol],       (char*)sA + w * 1024);
        gload16(&Bv2[(size_t)(n0 + (w + 4) * 16 + rs) * 256 + kk + scol], (char*)sA + (w + 4) * 1024);
        gload16(&Z1r[(size_t)(i0 + w * 16 + rs) * 256 + kk + scol],       (char*)sB + w * 1024);
        gload16(&Z1r[(size_t)(i0 + (w + 4) * 16 + rs) * 256 + kk + scol], (char*)sB + (w + 4) * 1024);
        __syncthreads();
        s16x8 af[4], bf[4];
        #pragma unroll
        for (int fm = 0; fm < 4; ++fm) {
            const int r = wm * 64 + fm * 16 + lane15;
            af[fm] = *(const s16x8*)&sA[r * 32 + ((q ^ fl) << 3)];
        }
        #pragma unroll
        for (int fn = 0; fn < 4; ++fn) {
            const int r = wn * 64 + fn * 16 + lane15;
            bf[fn] = *(const s16x8*)&sB[r * 32 + ((q ^ fl) << 3)];
        }
        #pragma unroll
        for (int fm = 0; fm < 4; ++fm)
            #pragma unroll
            for (int fn = 0; fn < 4; ++fn)
                acc[fm][fn] = __builtin_amdgcn_mfma_f32_16x16x32_bf16(af[fm], bf[fn], acc[fm][fn], 0, 0, 0);
        __syncthreads();
    }

    #pragma unroll
    for (int fm = 0; fm < 4; ++fm) {
        const int nbase = n0 + wm * 64 + fm * 16;
        const int j = nbase >> 5;
        const int k0 = (nbase & 31) + q * 4;
        #pragma unroll
        for (int fn = 0; fn < 4; ++fn) {
            const int i = i0 + wn * 64 + fn * 16 + lane15;
            s16x4 p;
            #pragma unroll
            for (int r = 0; r < 4; ++r) p[r] = (short)f2b(acc[fm][fn][r]);
            *(s16x4*)&X[(size_t)j * 32768 + i * 32 + k0] = p;
        }
    }
}

// ---------- fused conv1+leaky+conv2+leaky, NHWC, row-pipelined, y1 in LDS ----------
// Out tile 128x16. X ring: 3 rows x 134 px (gx0=x0-2); y1 ring: 3 rows x 130 px (base x0-1).
#define XW 134
#define XROW (XW * 32)          // shorts per X ring row (8576 B)
#define YW 130
#define YROW (YW * 32)          // shorts per y1 ring row (8320 B)
__global__ __launch_bounds__(256, 3) void fconv_kernel(const short* __restrict__ in,
                                                       const float* __restrict__ W1,
                                                       const float* __restrict__ b1,
                                                       const float* __restrict__ W2,
                                                       const float* __restrict__ b2,
                                                       float* __restrict__ out) {
    __shared__ short xr[3 * XROW];   // 25728 B
    __shared__ short yr[3 * YROW];   // 24960 B
    const int tid = threadIdx.x;
    const int w = tid >> 6, lane = tid & 63, lane15 = lane & 15, q = lane >> 4;
    const int bx = blockIdx.x, by = blockIdx.y;
    const int x0 = bx * 128, y0 = by * 16;
    const int gx0 = x0 - 2;          // X stage origin (rel px 0)

    // Both convs' weight A-frags in registers: A[o][c], o=mf*16+lane15, c=q*8+e
    s16x8 aw1[9][2], aw2[9][2];
    #pragma unroll
    for (int t = 0; t < 9; ++t)
        #pragma unroll
        for (int mf = 0; mf < 2; ++mf) {
            const int o = mf * 16 + lane15, c0 = q * 8;
            s16x8 a1, a2;
            #pragma unroll
            for (int e = 0; e < 8; ++e) {
                a1[e] = (short)f2b(W1[(o * 32 + c0 + e) * 9 + t]);
                a2[e] = (short)f2b(W2[(o * 32 + c0 + e) * 9 + t]);
            }
            aw1[t][mf] = a1; aw2[t][mf] = a2;
        }
    f32x4 bb1[2], bb2[2];
    #pragma unroll
    for (int mf = 0; mf < 2; ++mf) {
        bb1[mf] = *(const f32x4*)&b1[mf * 16 + q * 4];
        bb2[mf] = *(const f32x4*)&b2[mf * 16 + q * 4];
    }

    // persistent zeros for x-halo columns at image edges (stage skips OOB gx).
    // Barrier REQUIRED: zero-fill (ds_write, all waves, whole xr) must complete
    // before prologue gload16s land in xr — round-5 race lived here.
    if (bx == 0 || bx == 7) {
        s16x8* p = (s16x8*)xr;
        for (int i = tid; i < 3 * XW * 4; i += 256) p[i] = (s16x8)0;
        __syncthreads();
    }

    auto stage = [&](int rr) {                       // X image row y0+rr -> slot (rr+2)%3
        const int gy = y0 + rr;
        char* base = (char*)&xr[((rr + 2) % 3) * XROW];
        if ((unsigned)gy < 1024u) {
            #pragma unroll
            for (int it = 0; it < 3; ++it) {
                const int idx = it * 256 + tid;
                if (idx < XW * 4) {
                    const int px = idx >> 2, sseg = idx & 3;
                    const int gx = gx0 + px;
                    if ((unsigned)gx < 1024u)
                        gload16(&in[(size_t)((gy << 10) + gx) * 32 + ((sseg ^ swz(px)) << 3)],
                                base + (it * 256 + w * 64) * 16);
                }
            }
        } else {
            s16x8* b8 = (s16x8*)base;
            for (int idx = tid; idx < XW * 4; idx += 256) b8[idx] = (s16x8)0;
        }
    };

    auto y1_store = [&](const f32x4* acc, int n, int ysl) {
        const int pfx = n * 16 + lane15;             // y1 rel px (base x0-1)
        if (pfx < YW) {
            const int gx1 = x0 - 1 + pfx;
            const bool valid = (unsigned)gx1 < 1024u;    // conv2 zero-pads y1 at image edge
            #pragma unroll
            for (int mf = 0; mf < 2; ++mf) {
                s16x4 p;
                #pragma unroll
                for (int r = 0; r < 4; ++r) {
                    float f = acc[mf][r] + bb1[mf][r];
                    f = f >= 0.f ? f : 0.01f * f;
                    p[r] = valid ? (short)f2b(f) : (short)0;
                }
                const int u = mf * 4 + q, s = u >> 1, low = u & 1;
                *(s16x4*)&yr[ysl + pfx * 32 + ((s ^ swz(pfx)) << 3) + low * 4] = p;
            }
        }
    };

    auto compute_y1 = [&](int ry) {                  // y1 image row y0+ry -> slot (ry+3)%3
        const int gy1 = y0 + ry;
        const int ysl = ((ry + 3) % 3) * YROW;
        if ((unsigned)gy1 < 1024u) {
            int xs[3];
            #pragma unroll
            for (int dy = 0; dy < 3; ++dy) xs[dy] = ((ry + 1 + dy) % 3) * XROW;   // X row ry-1+dy
            f32x4 a0[2], a1[2], a2[2];
            #pragma unroll
            for (int mf = 0; mf < 2; ++mf) { a0[mf] = (f32x4)0; a1[mf] = (f32x4)0; a2[mf] = (f32x4)0; }
            #pragma unroll
            for (int dy = 0; dy < 3; ++dy)
                #pragma unroll
                for (int dx = 0; dx < 3; ++dx) {
                    const int t = dy * 3 + dx;
                    {
                        const int lpx = (w * 2) * 16 + lane15 + dx;
                        const s16x8 bfr = *(const s16x8*)&xr[xs[dy] + lpx * 32 + ((q ^ swz(lpx)) << 3)];
                        a0[0] = __builtin_amdgcn_mfma_f32_16x16x32_bf16(aw1[t][0], bfr, a0[0], 0, 0, 0);
                        a0[1] = __builtin_amdgcn_mfma_f32_16x16x32_bf16(aw1[t][1], bfr, a0[1], 0, 0, 0);
                    }
                    {
                        const int lpx = (w * 2 + 1) * 16 + lane15 + dx;
                        const s16x8 bfr = *(const s16x8*)&xr[xs[dy] + lpx * 32 + ((q ^ swz(lpx)) << 3)];
                        a1[0] = __builtin_amdgcn_mfma_f32_16x16x32_bf16(aw1[t][0], bfr, a1[0], 0, 0, 0);
                        a1[1] = __builtin_amdgcn_mfma_f32_16x16x32_bf16(aw1[t][1], bfr, a1[1], 0, 0, 0);
                    }
                    if (w == 0) {                    // tail tile (y1 px 128..129 stored)
                        const int lpx0 = 128 + lane15 + dx;
                        const int lpx = lpx0 < XW ? lpx0 : XW - 1;   // clamp: only unstored lanes hit it
                        const s16x8 bfr = *(const s16x8*)&xr[xs[dy] + lpx * 32 + ((q ^ swz(lpx)) << 3)];
                        a2[0] = __builtin_amdgcn_mfma_f32_16x16x32_bf16(aw1[t][0], bfr, a2[0], 0, 0, 0);
                        a2[1] = __builtin_amdgcn_mfma_f32_16x16x32_bf16(aw1[t][1], bfr, a2[1], 0, 0, 0);
                    }
                }
            y1_store(a0, w * 2, ysl);
            y1_store(a1, w * 2 + 1, ysl);
            if (w == 0) y1_store(a2, 8, ysl);
        } else {                                     // conv2 zero-padding row
            s16x8* b8 = (s16x8*)&yr[ysl];
            for (int idx = tid; idx < YW * 4; idx += 256) b8[idx] = (s16x8)0;
        }
    };

    auto compute_out = [&](int r) {                  // out image row y0+r
        const int gy = y0 + r;
        int ys[3];
        #pragma unroll
        for (int dy = 0; dy < 3; ++dy) ys[dy] = ((r + 2 + dy) % 3) * YROW;   // y1 row r-1+dy
        f32x4 acc[2][2];
        #pragma unroll
        for (int nf = 0; nf < 2; ++nf) { acc[nf][0] = (f32x4)0; acc[nf][1] = (f32x4)0; }
        #pragma unroll
        for (int dy = 0; dy < 3; ++dy)
            #pragma unroll
            for (int dx = 0; dx < 3; ++dx) {
                const int t = dy * 3 + dx;
                #pragma unroll
                for (int nf = 0; nf < 2; ++nf) {
                    const int lpx = w * 32 + nf * 16 + lane15 + dx;   // y1 rel (base x0-1)
                    const s16x8 bfr = *(const s16x8*)&yr[ys[dy] + lpx * 32 + ((q ^ swz(lpx)) << 3)];
                    acc[nf][0] = __builtin_amdgcn_mfma_f32_16x16x32_bf16(aw2[t][0], bfr, acc[nf][0], 0, 0, 0);
                    acc[nf][1] = __builtin_amdgcn_mfma_f32_16x16x32_bf16(aw2[t][1], bfr, acc[nf][1], 0, 0, 0);
                }
            }
        #pragma unroll
        for (int mf = 0; mf < 2; ++mf) {
            const int o4 = mf * 16 + q * 4;
            #pragma unroll
            for (int nf = 0; nf < 2; ++nf) {
                const int gx = x0 + w * 32 + nf * 16 + lane15;
                f32x4 v = acc[nf][mf];
                #pragma unroll
                for (int r4 = 0; r4 < 4; ++r4) {
                    v[r4] += bb2[mf][r4];
                    v[r4] = v[r4] >= 0.f ? v[r4] : 0.01f * v[r4];
                }
                *(f32x4*)&out[(((size_t)gy << 10) + gx) * 32 + o4] = v;
            }
        }
    };

    // prologue
    stage(-2); stage(-1); stage(0);
    __syncthreads();
    compute_y1(-1);
    __syncthreads();

    // main pipeline: stage(r+2) || out(r-1) | barrier | y1(r+1) | barrier
    for (int r = -1; r <= 15; ++r) {
        stage(r + 2);
        if (r > 0) compute_out(r - 1);
        __syncthreads();
        compute_y1(r + 1);
        __syncthreads();
    }
    compute_out(15);
}

extern "C" void kernel_launch(void* const* d_in, const int* in_sizes, int n_in,
                              void* d_out, int out_size, void* d_ws, size_t ws_size,
                              hipStream_t stream) {
    const float* Z1 = (const float*)d_in[0];
    const float* Z2 = (const float*)d_in[1];
    const float* Z3 = (const float*)d_in[2];
    const float* W1 = (const float*)d_in[3];
    const float* b1 = (const float*)d_in[4];
    const float* W2 = (const float*)d_in[5];
    const float* b2 = (const float*)d_in[6];

    // X (NHWC bf16, 67.1 MB) in ws; Bv2/Z1r in d_out-as-scratch (dead before fconv writes d_out)
    short* X   = (short*)d_ws;
    short* Bv2 = (short*)d_out;
    short* Z1r = Bv2 + 8388608;

    v_kernel  <<<1024, 256, 0, stream>>>(Z2, Z3, Bv2);
    z1r_kernel<<<64,   256, 0, stream>>>(Z1, Z1r);
    gemm_kernel<<<2048, 256, 0, stream>>>(Bv2, Z1r, X);
    fconv_kernel<<<dim3(8, 64), 256, 0, stream>>>(X, W1, b1, W2, b2, (float*)d_out);
}

// Round 7
// 250.906 us; speedup vs baseline: 1.4775x; 1.4775x over previous
//
#include <hip/hip_runtime.h>

typedef short  s16x4 __attribute__((ext_vector_type(4)));
typedef short  s16x8 __attribute__((ext_vector_type(8)));
typedef float  f32x4 __attribute__((ext_vector_type(4)));

__device__ __forceinline__ unsigned short f2b(float f) {
    unsigned u = __float_as_uint(f);
    u = u + 0x7FFFu + ((u >> 16) & 1u);   // RNE
    return (unsigned short)(u >> 16);
}

__device__ __forceinline__ void gload16(const void* g, void* l) {
    __builtin_amdgcn_global_load_lds((const __attribute__((address_space(1))) unsigned*)g,
                                     (__attribute__((address_space(3))) unsigned*)l,
                                     16, 0, 0);
}

// slot swizzle, period 16 in px: spreads per-pixel 16B channel-slots across banks
__device__ __forceinline__ int swz(int x) { return (x ^ (x >> 2)) & 3; }

// ---------- Bv2[(j*32+k)*256 + a*16+b] = sum_c Z2[b,j,c] * Z3[c,k,a]  (bf16) ----------
__global__ __launch_bounds__(256) void v_kernel(const float* __restrict__ Z2,
                                                const float* __restrict__ Z3,
                                                short* __restrict__ Bv2) {
    __shared__ float z3t[8192];   // [c][a][k]
    __shared__ float z2s[256];    // [b][c]
    const int tid = threadIdx.x, j = blockIdx.x;
    for (int t = tid; t < 8192; t += 256) {
        float v = Z3[t];                     // Z3[c,k,a] flat = c*512 + k*16 + a
        int c = t >> 9, k = (t >> 4) & 31, a = t & 15;
        z3t[c * 512 + a * 32 + k] = v;
    }
    z2s[tid] = Z2[(tid >> 4) * 16384 + j * 16 + (tid & 15)];
    __syncthreads();
    const int a = tid >> 4, b = tid & 15;
    float z2r[16];
    #pragma unroll
    for (int c = 0; c < 16; ++c) z2r[c] = z2s[b * 16 + c];
    float s[32];
    #pragma unroll
    for (int k = 0; k < 32; ++k) s[k] = 0.f;
    #pragma unroll
    for (int c = 0; c < 16; ++c) {
        #pragma unroll
        for (int k4 = 0; k4 < 8; ++k4) {
            f32x4 v = *(const f32x4*)&z3t[c * 512 + a * 32 + k4 * 4];
            #pragma unroll
            for (int r = 0; r < 4; ++r) s[k4 * 4 + r] += z2r[c] * v[r];
        }
    }
    #pragma unroll
    for (int k = 0; k < 32; ++k)
        Bv2[(size_t)(j * 32 + k) * 256 + tid] = (short)f2b(s[k]);
}

// ---------- Z1r[i*256 + a*16+b] = Z1[a,i,b]  (bf16) ----------
__global__ __launch_bounds__(256) void z1r_kernel(const float* __restrict__ Z1,
                                                  short* __restrict__ Z1r) {
    __shared__ float z1s[4096];
    const int tid = threadIdx.x, i0 = blockIdx.x * 16;
    #pragma unroll
    for (int a = 0; a < 16; ++a)
        z1s[a * 256 + tid] = Z1[a * 16384 + i0 * 16 + tid];
    __syncthreads();
    #pragma unroll
    for (int il = 0; il < 16; ++il)
        Z1r[(size_t)(i0 + il) * 256 + tid] =
            (short)f2b(z1s[(tid >> 4) * 256 + il * 16 + (tid & 15)]);
}

// ---------- X_nhwc[j][i][k] = sum_ab Bv2[(j*32+k)][ab] * Z1r[i][ab]  (bf16 MFMA) ----------
__global__ __launch_bounds__(256) void gemm_kernel(const short* __restrict__ Bv2,
                                                   const short* __restrict__ Z1r,
                                                   short* __restrict__ X) {
    __shared__ short sA[128 * 32];
    __shared__ short sB[128 * 32];
    const int tid = threadIdx.x;
    const int w = tid >> 6, lane = tid & 63, lane15 = lane & 15, q = lane >> 4;
    const int wm = w >> 1, wn = w & 1;
    const int bid = blockIdx.x;
    const int l = (bid & 7) * 256 + (bid >> 3);      // XCD-chunked swizzle
    const int n0 = (l >> 3) * 128, i0 = (l & 7) * 128;
    const int rs = lane >> 2, sp = lane & 3;
    const int scol = (sp ^ swz(rs)) << 3;
    const int fl = swz(lane15);

    f32x4 acc[4][4];
    #pragma unroll
    for (int a = 0; a < 4; ++a)
        #pragma unroll
        for (int b = 0; b < 4; ++b) acc[a][b] = (f32x4)0;

    for (int kk = 0; kk < 256; kk += 32) {
        gload16(&Bv2[(size_t)(n0 + w * 16 + rs) * 256 + kk + scol],       (char*)sA + w * 1024);
        gload16(&Bv2[(size_t)(n0 + (w + 4) * 16 + rs) * 256 + kk + scol], (char*)sA + (w + 4) * 1024);
        gload16(&Z1r[(size_t)(i0 + w * 16 + rs) * 256 + kk + scol],       (char*)sB + w * 1024);
        gload16(&Z1r[(size_t)(i0 + (w + 4) * 16 + rs) * 256 + kk + scol], (char*)sB + (w + 4) * 1024);
        __syncthreads();
        s16x8 af[4], bf[4];
        #pragma unroll
        for (int fm = 0; fm < 4; ++fm) {
            const int r = wm * 64 + fm * 16 + lane15;
            af[fm] = *(const s16x8*)&sA[r * 32 + ((q ^ fl) << 3)];
        }
        #pragma unroll
        for (int fn = 0; fn < 4; ++fn) {
            const int r = wn * 64 + fn * 16 + lane15;
            bf[fn] = *(const s16x8*)&sB[r * 32 + ((q ^ fl) << 3)];
        }
        #pragma unroll
        for (int fm = 0; fm < 4; ++fm)
            #pragma unroll
            for (int fn = 0; fn < 4; ++fn)
                acc[fm][fn] = __builtin_amdgcn_mfma_f32_16x16x32_bf16(af[fm], bf[fn], acc[fm][fn], 0, 0, 0);
        __syncthreads();
    }

    #pragma unroll
    for (int fm = 0; fm < 4; ++fm) {
        const int nbase = n0 + wm * 64 + fm * 16;
        const int j = nbase >> 5;
        const int k0 = (nbase & 31) + q * 4;
        #pragma unroll
        for (int fn = 0; fn < 4; ++fn) {
            const int i = i0 + wn * 64 + fn * 16 + lane15;
            s16x4 p;
            #pragma unroll
            for (int r = 0; r < 4; ++r) p[r] = (short)f2b(acc[fm][fn][r]);
            *(s16x4*)&X[(size_t)j * 32768 + i * 32 + k0] = p;
        }
    }
}

// ---------- fused conv1+leaky+conv2+leaky, NHWC, row-pipelined, y1 in LDS ----------
// Out tile 64x16, grid 16x64 (1024 blocks = 4/CU).
// Wave roles: mf = w&1 (o-channel half), xh = w>>1 (x-half) -> per-wave weights = 72 VGPR.
// X ring: 3 rows x 68 px (gx0 = x0-2); y1 ring: 3 rows x 66 px (base x0-1).
#define XW 68
#define XROW (XW * 32)          // shorts per X ring row (4352 B)
#define YW 66
#define YROW (YW * 32)          // shorts per y1 ring row (4224 B)
__global__ __launch_bounds__(256, 4) void fconv_kernel(const short* __restrict__ in,
                                                       const float* __restrict__ W1,
                                                       const float* __restrict__ b1,
                                                       const float* __restrict__ W2,
                                                       const float* __restrict__ b2,
                                                       float* __restrict__ out) {
    __shared__ short xr[3 * XROW];   // 13056 B
    __shared__ short yr[3 * YROW];   // 12672 B
    const int tid = threadIdx.x;
    const int w = tid >> 6, lane = tid & 63, lane15 = lane & 15, q = lane >> 4;
    const int mf = w & 1, xh = w >> 1;
    const int bx = blockIdx.x, by = blockIdx.y;
    const int x0 = bx * 64, y0 = by * 16;
    const int gx0 = x0 - 2;          // X stage origin (rel px 0)

    // per-wave weight A-frags (only our mf half): A[o][c], o = mf*16+lane15, c = q*8+e
    s16x8 aw1[9], aw2[9];
    {
        const int o = mf * 16 + lane15, c0 = q * 8;
        #pragma unroll
        for (int t = 0; t < 9; ++t) {
            s16x8 a1, a2;
            #pragma unroll
            for (int e = 0; e < 8; ++e) {
                a1[e] = (short)f2b(W1[(o * 32 + c0 + e) * 9 + t]);
                a2[e] = (short)f2b(W2[(o * 32 + c0 + e) * 9 + t]);
            }
            aw1[t] = a1; aw2[t] = a2;
        }
    }
    const f32x4 bb1 = *(const f32x4*)&b1[mf * 16 + q * 4];
    const f32x4 bb2 = *(const f32x4*)&b2[mf * 16 + q * 4];

    // persistent zeros for x-halo columns at image edges (stage skips OOB gx).
    // Barrier REQUIRED before any gload16 lands in xr (round-5 race lesson).
    if (bx == 0 || bx == 15) {
        s16x8* p = (s16x8*)xr;
        for (int i = tid; i < 3 * XW * 4; i += 256) p[i] = (s16x8)0;
        __syncthreads();
    }

    auto stage = [&](int rr) {                       // X image row y0+rr -> slot (rr+2)%3
        const int gy = y0 + rr;
        char* base = (char*)&xr[((rr + 2) % 3) * XROW];
        if ((unsigned)gy < 1024u) {
            #pragma unroll
            for (int it = 0; it < 2; ++it) {
                const int idx = it * 256 + tid;
                if (idx < XW * 4) {                  // 272 slots: it1 active only for tid<16
                    const int px = idx >> 2, sseg = idx & 3;
                    const int gx = gx0 + px;
                    if ((unsigned)gx < 1024u)
                        gload16(&in[(size_t)((gy << 10) + gx) * 32 + ((sseg ^ swz(px)) << 3)],
                                base + (it * 256 + w * 64) * 16);
                }
            }
        } else {
            s16x8* b8 = (s16x8*)base;
            for (int idx = tid; idx < XW * 4; idx += 256) b8[idx] = (s16x8)0;
        }
    };

    auto conv1_tile = [&](int tile, const int* xs) -> f32x4 {
        f32x4 a = (f32x4)0;
        #pragma unroll
        for (int dy = 0; dy < 3; ++dy)
            #pragma unroll
            for (int dx = 0; dx < 3; ++dx) {
                int lpx = tile * 16 + lane15 + dx;   // tail tile: clamp feeds discarded cols only
                lpx = lpx < XW ? lpx : XW - 1;
                const s16x8 bfr = *(const s16x8*)&xr[xs[dy] + lpx * 32 + ((q ^ swz(lpx)) << 3)];
                a = __builtin_amdgcn_mfma_f32_16x16x32_bf16(aw1[dy * 3 + dx], bfr, a, 0, 0, 0);
            }
        return a;
    };

    auto y1_store = [&](f32x4 a, int tile, int ysl) {
        const int pfx = tile * 16 + lane15;          // y1 rel px (base x0-1)
        if (pfx < YW) {
            const int gx1 = x0 - 1 + pfx;
            const bool valid = (unsigned)gx1 < 1024u;    // conv2 zero-pads y1 at image edge
            s16x4 p;
            #pragma unroll
            for (int r = 0; r < 4; ++r) {
                float f = a[r] + bb1[r];
                f = f >= 0.f ? f : 0.01f * f;
                p[r] = valid ? (short)f2b(f) : (short)0;
            }
            const int u = mf * 4 + q, s = u >> 1, low = u & 1;
            *(s16x4*)&yr[ysl + pfx * 32 + ((s ^ swz(pfx)) << 3) + low * 4] = p;
        }
    };

    auto compute_y1 = [&](int ry) {                  // y1 image row y0+ry -> slot (ry+3)%3
        const int gy1 = y0 + ry;
        const int ysl = ((ry + 3) % 3) * YROW;
        if ((unsigned)gy1 < 1024u) {
            int xs[3];
            #pragma unroll
            for (int dy = 0; dy < 3; ++dy) xs[dy] = ((ry + 1 + dy) % 3) * XROW;   // X row ry-1+dy
            if (xh == 0) {                           // tiles 0..2 (y1 px 0..47)
                f32x4 a0 = conv1_tile(0, xs);
                f32x4 a1 = conv1_tile(1, xs);
                f32x4 a2 = conv1_tile(2, xs);
                y1_store(a0, 0, ysl); y1_store(a1, 1, ysl); y1_store(a2, 2, ysl);
            } else {                                 // tiles 3..4 (y1 px 48..65, tail predicated)
                f32x4 a0 = conv1_tile(3, xs);
                f32x4 a1 = conv1_tile(4, xs);
                y1_store(a0, 3, ysl); y1_store(a1, 4, ysl);
            }
        } else {                                     // conv2 zero-padding row
            s16x8* b8 = (s16x8*)&yr[ysl];
            for (int idx = tid; idx < YW * 4; idx += 256) b8[idx] = (s16x8)0;
        }
    };

    auto compute_out = [&](int r) {                  // out image row y0+r
        const int gy = y0 + r;
        int ys[3];
        #pragma unroll
        for (int dy = 0; dy < 3; ++dy) ys[dy] = ((r + 2 + dy) % 3) * YROW;   // y1 row r-1+dy
        #pragma unroll
        for (int ti = 0; ti < 2; ++ti) {
            const int tile = xh * 2 + ti;
            f32x4 a = (f32x4)0;
            #pragma unroll
            for (int dy = 0; dy < 3; ++dy)
                #pragma unroll
                for (int dx = 0; dx < 3; ++dx) {
                    const int lpx = tile * 16 + lane15 + dx;   // <= 65, in range
                    const s16x8 bfr = *(const s16x8*)&yr[ys[dy] + lpx * 32 + ((q ^ swz(lpx)) << 3)];
                    a = __builtin_amdgcn_mfma_f32_16x16x32_bf16(aw2[dy * 3 + dx], bfr, a, 0, 0, 0);
                }
            const int gx = x0 + tile * 16 + lane15;
            const int o4 = mf * 16 + q * 4;
            f32x4 v = a;
            #pragma unroll
            for (int r4 = 0; r4 < 4; ++r4) {
                v[r4] += bb2[r4];
                v[r4] = v[r4] >= 0.f ? v[r4] : 0.01f * v[r4];
            }
            *(f32x4*)&out[(((size_t)gy << 10) + gx) * 32 + o4] = v;
        }
    };

    // prologue
    stage(-2); stage(-1); stage(0);
    __syncthreads();
    compute_y1(-1);
    __syncthreads();

    // main pipeline: stage(r+2) || out(r-1) | barrier | y1(r+1) | barrier
    for (int r = -1; r <= 15; ++r) {
        stage(r + 2);
        if (r > 0) compute_out(r - 1);
        __syncthreads();
        compute_y1(r + 1);
        __syncthreads();
    }
    compute_out(15);
}

extern "C" void kernel_launch(void* const* d_in, const int* in_sizes, int n_in,
                              void* d_out, int out_size, void* d_ws, size_t ws_size,
                              hipStream_t stream) {
    const float* Z1 = (const float*)d_in[0];
    const float* Z2 = (const float*)d_in[1];
    const float* Z3 = (const float*)d_in[2];
    const float* W1 = (const float*)d_in[3];
    const float* b1 = (const float*)d_in[4];
    const float* W2 = (const float*)d_in[5];
    const float* b2 = (const float*)d_in[6];

    // X (NHWC bf16, 67.1 MB) in ws; Bv2/Z1r in d_out-as-scratch (dead before fconv writes d_out)
    short* X   = (short*)d_ws;
    short* Bv2 = (short*)d_out;
    short* Z1r = Bv2 + 8388608;

    v_kernel  <<<1024, 256, 0, stream>>>(Z2, Z3, Bv2);
    z1r_kernel<<<64,   256, 0, stream>>>(Z1, Z1r);
    gemm_kernel<<<2048, 256, 0, stream>>>(Bv2, Z1r, X);
    fconv_kernel<<<dim3(16, 64), 256, 0, stream>>>(X, W1, b1, W2, b2, (float*)d_out);
}

// Round 8
// 141.875 us; speedup vs baseline: 2.6130x; 1.7685x over previous
//
#include <hip/hip_runtime.h>

typedef short  s16x4 __attribute__((ext_vector_type(4)));
typedef short  s16x8 __attribute__((ext_vector_type(8)));
typedef float  f32x4 __attribute__((ext_vector_type(4)));

__device__ __forceinline__ unsigned short f2b(float f) {
    unsigned u = __float_as_uint(f);
    u = u + 0x7FFFu + ((u >> 16) & 1u);   // RNE
    return (unsigned short)(u >> 16);
}

__device__ __forceinline__ void gload16(const void* g, void* l) {
    __builtin_amdgcn_global_load_lds((const __attribute__((address_space(1))) unsigned*)g,
                                     (__attribute__((address_space(3))) unsigned*)l,
                                     16, 0, 0);
}

// slot swizzle, period 16 in px: spreads per-pixel 16B channel-slots across banks
__device__ __forceinline__ int swz(int x) { return (x ^ (x >> 2)) & 3; }

// ---------- Bv2[(j*32+k)*256 + a*16+b] = sum_c Z2[b,j,c] * Z3[c,k,a]  (bf16) ----------
__global__ __launch_bounds__(256) void v_kernel(const float* __restrict__ Z2,
                                                const float* __restrict__ Z3,
                                                short* __restrict__ Bv2) {
    __shared__ float z3t[8192];   // [c][a][k]
    __shared__ float z2s[256];    // [b][c]
    const int tid = threadIdx.x, j = blockIdx.x;
    for (int t = tid; t < 8192; t += 256) {
        float v = Z3[t];                     // Z3[c,k,a] flat = c*512 + k*16 + a
        int c = t >> 9, k = (t >> 4) & 31, a = t & 15;
        z3t[c * 512 + a * 32 + k] = v;
    }
    z2s[tid] = Z2[(tid >> 4) * 16384 + j * 16 + (tid & 15)];
    __syncthreads();
    const int a = tid >> 4, b = tid & 15;
    float z2r[16];
    #pragma unroll
    for (int c = 0; c < 16; ++c) z2r[c] = z2s[b * 16 + c];
    float s[32];
    #pragma unroll
    for (int k = 0; k < 32; ++k) s[k] = 0.f;
    #pragma unroll
    for (int c = 0; c < 16; ++c) {
        #pragma unroll
        for (int k4 = 0; k4 < 8; ++k4) {
            f32x4 v = *(const f32x4*)&z3t[c * 512 + a * 32 + k4 * 4];
            #pragma unroll
            for (int r = 0; r < 4; ++r) s[k4 * 4 + r] += z2r[c] * v[r];
        }
    }
    #pragma unroll
    for (int k = 0; k < 32; ++k)
        Bv2[(size_t)(j * 32 + k) * 256 + tid] = (short)f2b(s[k]);
}

// ---------- Z1r[i*256 + a*16+b] = Z1[a,i,b]  (bf16) ----------
__global__ __launch_bounds__(256) void z1r_kernel(const float* __restrict__ Z1,
                                                  short* __restrict__ Z1r) {
    __shared__ float z1s[4096];
    const int tid = threadIdx.x, i0 = blockIdx.x * 16;
    #pragma unroll
    for (int a = 0; a < 16; ++a)
        z1s[a * 256 + tid] = Z1[a * 16384 + i0 * 16 + tid];
    __syncthreads();
    #pragma unroll
    for (int il = 0; il < 16; ++il)
        Z1r[(size_t)(i0 + il) * 256 + tid] =
            (short)f2b(z1s[(tid >> 4) * 256 + il * 16 + (tid & 15)]);
}

// ---------- X_nhwc[j][i][k] = sum_ab Bv2[(j*32+k)][ab] * Z1r[i][ab]  (bf16 MFMA) ----------
__global__ __launch_bounds__(256) void gemm_kernel(const short* __restrict__ Bv2,
                                                   const short* __restrict__ Z1r,
                                                   short* __restrict__ X) {
    __shared__ short sA[128 * 32];
    __shared__ short sB[128 * 32];
    const int tid = threadIdx.x;
    const int w = tid >> 6, lane = tid & 63, lane15 = lane & 15, q = lane >> 4;
    const int wm = w >> 1, wn = w & 1;
    const int bid = blockIdx.x;
    const int l = (bid & 7) * 256 + (bid >> 3);      // XCD-chunked swizzle
    const int n0 = (l >> 3) * 128, i0 = (l & 7) * 128;
    const int rs = lane >> 2, sp = lane & 3;
    const int scol = (sp ^ swz(rs)) << 3;
    const int fl = swz(lane15);

    f32x4 acc[4][4];
    #pragma unroll
    for (int a = 0; a < 4; ++a)
        #pragma unroll
        for (int b = 0; b < 4; ++b) acc[a][b] = (f32x4)0;

    for (int kk = 0; kk < 256; kk += 32) {
        gload16(&Bv2[(size_t)(n0 + w * 16 + rs) * 256 + kk + scol],       (char*)sA + w * 1024);
        gload16(&Bv2[(size_t)(n0 + (w + 4) * 16 + rs) * 256 + kk + scol], (char*)sA + (w + 4) * 1024);
        gload16(&Z1r[(size_t)(i0 + w * 16 + rs) * 256 + kk + scol],       (char*)sB + w * 1024);
        gload16(&Z1r[(size_t)(i0 + (w + 4) * 16 + rs) * 256 + kk + scol], (char*)sB + (w + 4) * 1024);
        __syncthreads();
        s16x8 af[4], bf[4];
        #pragma unroll
        for (int fm = 0; fm < 4; ++fm) {
            const int r = wm * 64 + fm * 16 + lane15;
            af[fm] = *(const s16x8*)&sA[r * 32 + ((q ^ fl) << 3)];
        }
        #pragma unroll
        for (int fn = 0; fn < 4; ++fn) {
            const int r = wn * 64 + fn * 16 + lane15;
            bf[fn] = *(const s16x8*)&sB[r * 32 + ((q ^ fl) << 3)];
        }
        #pragma unroll
        for (int fm = 0; fm < 4; ++fm)
            #pragma unroll
            for (int fn = 0; fn < 4; ++fn)
                acc[fm][fn] = __builtin_amdgcn_mfma_f32_16x16x32_bf16(af[fm], bf[fn], acc[fm][fn], 0, 0, 0);
        __syncthreads();
    }

    #pragma unroll
    for (int fm = 0; fm < 4; ++fm) {
        const int nbase = n0 + wm * 64 + fm * 16;
        const int j = nbase >> 5;
        const int k0 = (nbase & 31) + q * 4;
        #pragma unroll
        for (int fn = 0; fn < 4; ++fn) {
            const int i = i0 + wn * 64 + fn * 16 + lane15;
            s16x4 p;
            #pragma unroll
            for (int r = 0; r < 4; ++r) p[r] = (short)f2b(acc[fm][fn][r]);
            *(s16x4*)&X[(size_t)j * 32768 + i * 32 + k0] = p;
        }
    }
}

// ---------- fused conv1+leaky+conv2+leaky, NHWC, row-pipelined, y1 in LDS ----------
// Out tile 64x16, grid 16x64 (1024 blocks = 4/CU by LDS; occupancy via NATURAL VGPR demand).
// NOTE: no min-waves in __launch_bounds__ — rounds 6/7 showed the cap halves the
// effective VGPR budget (arg 2/3/4 -> alloc 128/84/64) and force-spills the 72-VGPR
// weight set to scratch (FETCH 375/489 MB). Natural demand ~110-130 -> 4 waves/SIMD.
// Wave roles: mf = w&1 (o-channel half), xh = w>>1 (x-half) -> per-wave weights = 72 VGPR.
// X ring: 3 rows x 68 px (gx0 = x0-2); y1 ring: 3 rows x 66 px (base x0-1).
#define XW 68
#define XROW (XW * 32)          // shorts per X ring row (4352 B)
#define YW 66
#define YROW (YW * 32)          // shorts per y1 ring row (4224 B)
__global__ __launch_bounds__(256) void fconv_kernel(const short* __restrict__ in,
                                                    const float* __restrict__ W1,
                                                    const float* __restrict__ b1,
                                                    const float* __restrict__ W2,
                                                    const float* __restrict__ b2,
                                                    float* __restrict__ out) {
    __shared__ short xr[3 * XROW];   // 13056 B
    __shared__ short yr[3 * YROW];   // 12672 B
    const int tid = threadIdx.x;
    const int w = tid >> 6, lane = tid & 63, lane15 = lane & 15, q = lane >> 4;
    const int mf = w & 1, xh = w >> 1;
    const int bx = blockIdx.x, by = blockIdx.y;
    const int x0 = bx * 64, y0 = by * 16;
    const int gx0 = x0 - 2;          // X stage origin (rel px 0)

    // per-wave weight A-frags (only our mf half): A[o][c], o = mf*16+lane15, c = q*8+e
    s16x8 aw1[9], aw2[9];
    {
        const int o = mf * 16 + lane15, c0 = q * 8;
        #pragma unroll
        for (int t = 0; t < 9; ++t) {
            s16x8 a1, a2;
            #pragma unroll
            for (int e = 0; e < 8; ++e) {
                a1[e] = (short)f2b(W1[(o * 32 + c0 + e) * 9 + t]);
                a2[e] = (short)f2b(W2[(o * 32 + c0 + e) * 9 + t]);
            }
            aw1[t] = a1; aw2[t] = a2;
        }
    }
    const f32x4 bb1 = *(const f32x4*)&b1[mf * 16 + q * 4];
    const f32x4 bb2 = *(const f32x4*)&b2[mf * 16 + q * 4];

    // persistent zeros for x-halo columns at image edges (stage skips OOB gx).
    // Barrier REQUIRED before any gload16 lands in xr (round-5 race lesson).
    if (bx == 0 || bx == 15) {
        s16x8* p = (s16x8*)xr;
        for (int i = tid; i < 3 * XW * 4; i += 256) p[i] = (s16x8)0;
        __syncthreads();
    }

    auto stage = [&](int rr) {                       // X image row y0+rr -> slot (rr+2)%3
        const int gy = y0 + rr;
        char* base = (char*)&xr[((rr + 2) % 3) * XROW];
        if ((unsigned)gy < 1024u) {
            #pragma unroll
            for (int it = 0; it < 2; ++it) {
                const int idx = it * 256 + tid;
                if (idx < XW * 4) {                  // 272 slots: it1 active only for tid<16
                    const int px = idx >> 2, sseg = idx & 3;
                    const int gx = gx0 + px;
                    if ((unsigned)gx < 1024u)
                        gload16(&in[(size_t)((gy << 10) + gx) * 32 + ((sseg ^ swz(px)) << 3)],
                                base + (it * 256 + w * 64) * 16);
                }
            }
        } else {
            s16x8* b8 = (s16x8*)base;
            for (int idx = tid; idx < XW * 4; idx += 256) b8[idx] = (s16x8)0;
        }
    };

    auto conv1_tile = [&](int tile, const int* xs) -> f32x4 {
        f32x4 a = (f32x4)0;
        #pragma unroll
        for (int dy = 0; dy < 3; ++dy)
            #pragma unroll
            for (int dx = 0; dx < 3; ++dx) {
                int lpx = tile * 16 + lane15 + dx;   // tail tile: clamp feeds discarded cols only
                lpx = lpx < XW ? lpx : XW - 1;
                const s16x8 bfr = *(const s16x8*)&xr[xs[dy] + lpx * 32 + ((q ^ swz(lpx)) << 3)];
                a = __builtin_amdgcn_mfma_f32_16x16x32_bf16(aw1[dy * 3 + dx], bfr, a, 0, 0, 0);
            }
        return a;
    };

    auto y1_store = [&](f32x4 a, int tile, int ysl) {
        const int pfx = tile * 16 + lane15;          // y1 rel px (base x0-1)
        if (pfx < YW) {
            const int gx1 = x0 - 1 + pfx;
            const bool valid = (unsigned)gx1 < 1024u;    // conv2 zero-pads y1 at image edge
            s16x4 p;
            #pragma unroll
            for (int r = 0; r < 4; ++r) {
                float f = a[r] + bb1[r];
                f = f >= 0.f ? f : 0.01f * f;
                p[r] = valid ? (short)f2b(f) : (short)0;
            }
            const int u = mf * 4 + q, s = u >> 1, low = u & 1;
            *(s16x4*)&yr[ysl + pfx * 32 + ((s ^ swz(pfx)) << 3) + low * 4] = p;
        }
    };

    auto compute_y1 = [&](int ry) {                  // y1 image row y0+ry -> slot (ry+3)%3
        const int gy1 = y0 + ry;
        const int ysl = ((ry + 3) % 3) * YROW;
        if ((unsigned)gy1 < 1024u) {
            int xs[3];
            #pragma unroll
            for (int dy = 0; dy < 3; ++dy) xs[dy] = ((ry + 1 + dy) % 3) * XROW;   // X row ry-1+dy
            if (xh == 0) {                           // tiles 0..2 (y1 px 0..47)
                f32x4 a0 = conv1_tile(0, xs);
                f32x4 a1 = conv1_tile(1, xs);
                f32x4 a2 = conv1_tile(2, xs);
                y1_store(a0, 0, ysl); y1_store(a1, 1, ysl); y1_store(a2, 2, ysl);
            } else {                                 // tiles 3..4 (y1 px 48..65, tail predicated)
                f32x4 a0 = conv1_tile(3, xs);
                f32x4 a1 = conv1_tile(4, xs);
                y1_store(a0, 3, ysl); y1_store(a1, 4, ysl);
            }
        } else {                                     // conv2 zero-padding row
            s16x8* b8 = (s16x8*)&yr[ysl];
            for (int idx = tid; idx < YW * 4; idx += 256) b8[idx] = (s16x8)0;
        }
    };

    auto compute_out = [&](int r) {                  // out image row y0+r
        const int gy = y0 + r;
        int ys[3];
        #pragma unroll
        for (int dy = 0; dy < 3; ++dy) ys[dy] = ((r + 2 + dy) % 3) * YROW;   // y1 row r-1+dy
        #pragma unroll
        for (int ti = 0; ti < 2; ++ti) {
            const int tile = xh * 2 + ti;
            f32x4 a = (f32x4)0;
            #pragma unroll
            for (int dy = 0; dy < 3; ++dy)
                #pragma unroll
                for (int dx = 0; dx < 3; ++dx) {
                    const int lpx = tile * 16 + lane15 + dx;   // <= 65, in range
                    const s16x8 bfr = *(const s16x8*)&yr[ys[dy] + lpx * 32 + ((q ^ swz(lpx)) << 3)];
                    a = __builtin_amdgcn_mfma_f32_16x16x32_bf16(aw2[dy * 3 + dx], bfr, a, 0, 0, 0);
                }
            const int gx = x0 + tile * 16 + lane15;
            const int o4 = mf * 16 + q * 4;
            f32x4 v = a;
            #pragma unroll
            for (int r4 = 0; r4 < 4; ++r4) {
                v[r4] += bb2[r4];
                v[r4] = v[r4] >= 0.f ? v[r4] : 0.01f * v[r4];
            }
            *(f32x4*)&out[(((size_t)gy << 10) + gx) * 32 + o4] = v;
        }
    };

    // prologue
    stage(-2); stage(-1); stage(0);
    __syncthreads();
    compute_y1(-1);
    __syncthreads();

    // main pipeline: stage(r+2) || out(r-1) | barrier | y1(r+1) | barrier
    for (int r = -1; r <= 15; ++r) {
        stage(r + 2);
        if (r > 0) compute_out(r - 1);
        __syncthreads();
        compute_y1(r + 1);
        __syncthreads();
    }
    compute_out(15);
}

extern "C" void kernel_launch(void* const* d_in, const int* in_sizes, int n_in,
                              void* d_out, int out_size, void* d_ws, size_t ws_size,
                              hipStream_t stream) {
    const float* Z1 = (const float*)d_in[0];
    const float* Z2 = (const float*)d_in[1];
    const float* Z3 = (const float*)d_in[2];
    const float* W1 = (const float*)d_in[3];
    const float* b1 = (const float*)d_in[4];
    const float* W2 = (const float*)d_in[5];
    const float* b2 = (const float*)d_in[6];

    // X (NHWC bf16, 67.1 MB) in ws; Bv2/Z1r in d_out-as-scratch (dead before fconv writes d_out)
    short* X   = (short*)d_ws;
    short* Bv2 = (short*)d_out;
    short* Z1r = Bv2 + 8388608;

    v_kernel  <<<1024, 256, 0, stream>>>(Z2, Z3, Bv2);
    z1r_kernel<<<64,   256, 0, stream>>>(Z1, Z1r);
    gemm_kernel<<<2048, 256, 0, stream>>>(Bv2, Z1r, X);
    fconv_kernel<<<dim3(16, 64), 256, 0, stream>>>(X, W1, b1, W2, b2, (float*)d_out);
}